// Round 4
// baseline (958.028 us; speedup 1.0000x reference)
//
#include <hip/hip_runtime.h>
#include <hip/hip_bf16.h>

#define NPOS 262144   // 4 * 256 * 256

typedef short bf16x8 __attribute__((ext_vector_type(8)));
typedef float f32x4 __attribute__((ext_vector_type(4)));

__device__ __forceinline__ unsigned short f2bf(float f) {
    union { float f; unsigned u; } v; v.f = f;
    unsigned r = v.u + 0x7fffu + ((v.u >> 16) & 1u);
    return (unsigned short)(r >> 16);
}
__device__ __forceinline__ float bf2f(unsigned short h) {
    union { unsigned u; float f; } v; v.u = ((unsigned)h) << 16;
    return v.f;
}
__device__ __forceinline__ float bflo(unsigned d) {
    union { unsigned u; float f; } v; v.u = d << 16;
    return v.f;
}
__device__ __forceinline__ float bfhi(unsigned d) {
    union { unsigned u; float f; } v; v.u = d & 0xffff0000u;
    return v.f;
}
__device__ __forceinline__ float gelu_tanh(float x) {
    float u = 0.7978845608028654f * (x + 0.044715f * x * x * x);
    float t = 1.0f - 2.0f / (__expf(2.0f * u) + 1.0f);
    return 0.5f * x * (1.0f + t);
}
// XOR bank swizzle: involution, flips byte-addr bits [6:4] with bits [9:7].
__device__ __forceinline__ int swz(int o) {
    return o ^ (((o >> 7) & 7) << 4);
}

// async global -> LDS, 16B per lane. LDS dest is wave-uniform base + lane*16.
__device__ __forceinline__ void gl2lds16(const unsigned short* __restrict__ g, unsigned short* l) {
    __builtin_amdgcn_global_load_lds(
        (const __attribute__((address_space(1))) unsigned int*)(const void*)g,
        (__attribute__((address_space(3))) unsigned int*)(void*)l,
        16, 0, 0);
}

// ---------------- utility ----------------
__global__ void k_fillz(float* __restrict__ p, int n) {
    int i = blockIdx.x * 256 + threadIdx.x;
    if (i < n) p[i] = 0.f;
}
__global__ void k_f32_to_bf16(const float* __restrict__ src, unsigned short* __restrict__ dst, int n) {
    int i = blockIdx.x * 256 + threadIdx.x;
    if (i < n) dst[i] = f2bf(src[i]);
}

// zero the two pad columns (wp=0, wp=257) of the padded y1 buffer [4][256][258][96]
__global__ void k_fillpad(unsigned* __restrict__ y1p32) {
    int i = blockIdx.x * 256 + threadIdx.x;   // < 98304 = 1024*2*48
    if (i >= 98304) return;
    int pos = i / 48, c2 = i % 48;
    int bh = pos >> 1, side = pos & 1;
    size_t o = ((size_t)bh * 258 + (size_t)side * 257) * 48 + c2;
    y1p32[o] = 0u;
}

// Combined qkv weight: Wc[tap][co][ci] = sum_k w2[co][k][tap] * w1[k][ci]
__global__ void k_combine_qkv(const float* __restrict__ w2, const float* __restrict__ w1,
        unsigned short* __restrict__ out) {
    int bx = blockIdx.x;           // 9*288
    int tap = bx / 288, co = bx % 288;
    int ci = threadIdx.x;          // 96
    const float* w2p = w2 + (size_t)co * 2592 + tap;
    float acc = 0.f;
    for (int k = 0; k < 288; k++)
        acc += w2p[k * 9] * w1[k * 96 + ci];
    out[((size_t)tap * 288 + co) * 96 + ci] = f2bf(acc);
}

// Combined apply+proj weight: Wb[b][n][m] = sum_j proj_w[n][hd(m)*16+j] * attnW[b][hd(m)*16+j][ck(m)]
__global__ void k_combine_wb(const float* __restrict__ proj_w, const float* __restrict__ attnW,
        unsigned short* __restrict__ Wb) {
    int bx = blockIdx.x;          // 4*96
    int b = bx / 96, n = bx % 96;
    int m = threadIdx.x;          // 96
    int hd = m >> 4, ck = m & 15;
    float acc = 0.f;
    #pragma unroll
    for (int j = 0; j < 16; j++)
        acc += proj_w[n * 96 + hd * 16 + j] * attnW[(size_t)b * 1536 + (hd * 16 + j) * 16 + ck];
    Wb[((size_t)b * 96 + n) * 96 + m] = f2bf(acc);
}

// ---------------- LN1: NCHW fp32 -> xres (NHWC bf16) + y1p (padded NHWC bf16) ----------------
__global__ __launch_bounds__(256) void k_ln1(const float* __restrict__ x,
        const float* __restrict__ lnw, const float* __restrict__ lnb,
        unsigned short* __restrict__ xres, unsigned short* __restrict__ y1p) {
    __shared__ float tile[96 * 65];
    __shared__ float smu[64], srs[64];
    const int t = threadIdx.x;
    const int p0 = blockIdx.x * 64;
    const int b = p0 >> 16, hw0 = p0 & 65535;
    const int h = hw0 >> 8, w0 = hw0 & 255;
    const size_t padbase = ((size_t)(b * 256 + h) * 258 + (w0 + 1)) * 96;
    #pragma unroll
    for (int i = 0; i < 24; i++) {
        int g = i * 256 + t;
        int c = g >> 6, pos = g & 63;
        tile[c * 65 + pos] = x[(size_t)(b * 96 + c) * 65536 + hw0 + pos];
    }
    __syncthreads();
    if (t < 64) {
        float s = 0.f, s2 = 0.f;
        for (int c = 0; c < 96; c++) { float v = tile[c * 65 + t]; s += v; s2 += v * v; }
        float mu = s * (1.0f / 96.0f);
        float var = s2 * (1.0f / 96.0f) - mu * mu;
        smu[t] = mu; srs[t] = rsqrtf(var + 1e-5f);
    }
    __syncthreads();
    #pragma unroll
    for (int i = 0; i < 12; i++) {
        int g2 = (i * 256 + t) * 2;
        int pos = g2 / 96, c = g2 % 96;
        float v0 = tile[c * 65 + pos], v1 = tile[(c + 1) * 65 + pos];
        float mu = smu[pos], rs = srs[pos];
        size_t o = (size_t)(p0 + pos) * 96 + c;
        *(unsigned*)(xres + o) = (unsigned)f2bf(v0) | ((unsigned)f2bf(v1) << 16);
        unsigned short a0 = f2bf((v0 - mu) * rs * lnw[c] + lnb[c]);
        unsigned short a1 = f2bf((v1 - mu) * rs * lnw[c + 1] + lnb[c + 1]);
        *(unsigned*)(y1p + padbase + (size_t)pos * 96 + c) = (unsigned)a0 | ((unsigned)a1 << 16);
    }
}

// ---------------- LN2: NHWC fp32 -> NHWC bf16 ----------------
__global__ __launch_bounds__(256) void k_ln2(const float* __restrict__ xin,
        const float* __restrict__ lnw, const float* __restrict__ lnb,
        unsigned short* __restrict__ y2) {
    __shared__ float tile[64 * 97];
    __shared__ float smu[64], srs[64];
    const int t = threadIdx.x;
    const int p0 = blockIdx.x * 64;
    #pragma unroll
    for (int i = 0; i < 24; i++) {
        int g = i * 256 + t;
        int pos = g / 96, c = g % 96;
        tile[pos * 97 + c] = xin[(size_t)p0 * 96 + g];
    }
    __syncthreads();
    if (t < 64) {
        float s = 0.f, s2 = 0.f;
        for (int c = 0; c < 96; c++) { float v = tile[t * 97 + c]; s += v; s2 += v * v; }
        float mu = s * (1.0f / 96.0f);
        float var = s2 * (1.0f / 96.0f) - mu * mu;
        smu[t] = mu; srs[t] = rsqrtf(var + 1e-5f);
    }
    __syncthreads();
    #pragma unroll
    for (int i = 0; i < 12; i++) {
        int g2 = (i * 256 + t) * 2;
        int pos = g2 / 96, c = g2 % 96;
        float mu = smu[pos], rs = srs[pos];
        unsigned short a0 = f2bf((tile[pos * 97 + c] - mu) * rs * lnw[c] + lnb[c]);
        unsigned short a1 = f2bf((tile[pos * 97 + c + 1] - mu) * rs * lnw[c + 1] + lnb[c + 1]);
        *(unsigned*)(y2 + (size_t)p0 * 96 + g2) = (unsigned)a0 | ((unsigned)a1 << 16);
    }
}

// ---------------- NHWC fp32 -> NCHW fp32 (final output) ----------------
__global__ __launch_bounds__(256) void k_tout(const float* __restrict__ xin, float* __restrict__ out) {
    __shared__ float tile[96 * 65];
    const int t = threadIdx.x;
    const int p0 = blockIdx.x * 64;
    const int b = p0 >> 16, hw0 = p0 & 65535;
    #pragma unroll
    for (int i = 0; i < 24; i++) {
        int g = i * 256 + t;
        int pos = g / 96, c = g % 96;
        tile[c * 65 + pos] = xin[(size_t)p0 * 96 + g];
    }
    __syncthreads();
    #pragma unroll
    for (int i = 0; i < 24; i++) {
        int g = i * 256 + t;
        int c = g >> 6, pos = g & 63;
        out[(size_t)(b * 96 + c) * 65536 + hw0 + pos] = tile[c * 65 + pos];
    }
}

// ---------------- qkv 3x3 conv: barrier-free MFMA loop ----------------
// A: padded y1 [4][256][258][96] bf16, direct global->reg per kk.
// B: Wcomb [9][288][96] bf16 (L1/L2-hot, ~82KB working set per block), direct
//    global->reg per kk. NO LDS, NO barriers in the main loop: waves run free,
//    latency hidden by occupancy (24KB LDS epilogue-only -> 5-6 blocks/CU).
__global__ __launch_bounds__(256, 4) void k_qkvconv(
        const unsigned short* __restrict__ Ap,
        const unsigned short* __restrict__ W,
        unsigned short* __restrict__ OUT) {
    __shared__ unsigned short Ds[12288];   // epilogue staging only (24 KB)
    const int t = threadIdx.x;
    const int wv = t >> 6, lane = t & 63;
    const int wr = wv >> 1, wc = wv & 1;
    const int quad = lane >> 4, lrow = lane & 15;

    // bijective XCD swizzle: 6144 blocks, 8 XCDs, 768/chunk
    const int lin = blockIdx.y * 3 + blockIdx.x;
    const int sw = (lin & 7) * 768 + (lin >> 3);
    const int co0 = (sw % 3) * 96;
    const int p0 = (sw / 3) * 128;

    const int b = p0 >> 16;
    const int hw0 = p0 & 65535;
    const int h = hw0 >> 8, w0 = hw0 & 255;

    const int tfirst = (h == 0) ? 3 : 0;
    const int nv = (h == 0 || h == 255) ? 6 : 9;

    // A row pointers (center tap): rows wr*64+lrow and wr*64+32+lrow
    const unsigned short* arowA;
    {
        const size_t base = ((size_t)(b * 256 + h) * 258 + (w0 + 1)) * 96;
        arowA = Ap + base + (size_t)(wr * 64 + lrow) * 96 + quad * 8;
    }
    const unsigned short* arowB = arowA + 32 * 96;

    // B fragment base: row co0 + wc*48 + lrow, col quad*8; nt -> +nt*16*96, kk -> +kk*32
    const unsigned short* brow = W + (size_t)(co0 + wc * 48 + lrow) * 96 + quad * 8;

    f32x4 acc[4][3];
    f32x4 zero = {0.f, 0.f, 0.f, 0.f};
    #pragma unroll
    for (int i = 0; i < 4; i++)
        #pragma unroll
        for (int j = 0; j < 3; j++) acc[i][j] = zero;

    for (int i = 0; i < nv; i++) {
        const int tp = tfirst + i;
        const int doff = ((tp / 3) - 1) * (258 * 96) + ((tp % 3) - 1) * 96;
        const unsigned short* pA = arowA + doff;
        const unsigned short* pB = arowB + doff;
        const unsigned short* pW = brow + (size_t)tp * 27648;
        #pragma unroll
        for (int kk = 0; kk < 3; kk++) {
            bf16x8 a[4], bb[3];
            a[0] = *(const bf16x8*)(pA + kk * 32);
            a[1] = *(const bf16x8*)(pA + 1536 + kk * 32);
            a[2] = *(const bf16x8*)(pB + kk * 32);
            a[3] = *(const bf16x8*)(pB + 1536 + kk * 32);
            #pragma unroll
            for (int nt = 0; nt < 3; nt++)
                bb[nt] = *(const bf16x8*)(pW + nt * 1536 + kk * 32);
            #pragma unroll
            for (int mt = 0; mt < 4; mt++)
                #pragma unroll
                for (int nt = 0; nt < 3; nt++)
                    acc[mt][nt] = __builtin_amdgcn_mfma_f32_16x16x32_bf16(a[mt], bb[nt], acc[mt][nt], 0, 0, 0);
        }
    }

    // epilogue: stage 128x96 bf16 through LDS (swizzled), vectorized store
    char* Dp = (char*)Ds;
    #pragma unroll
    for (int mt = 0; mt < 4; mt++)
        #pragma unroll
        for (int nt = 0; nt < 3; nt++)
            #pragma unroll
            for (int r = 0; r < 4; r++) {
                int o = ((wr * 64 + mt * 16 + quad * 4 + r) * 96 + wc * 48 + nt * 16 + lrow) * 2;
                *(unsigned short*)(Dp + swz(o)) = f2bf(acc[mt][nt][r]);
            }
    __syncthreads();
    #pragma unroll
    for (int i = 0; i < 6; i++) {
        int g = i * 256 + t;
        int row = g / 12, u = g % 12;
        int o = swz(row * 192 + u * 16);
        *(uint4*)(OUT + (size_t)(p0 + row) * 288 + co0 + u * 8) = *(const uint4*)(Dp + o);
    }
}

// ---------------- generic 1x1 MFMA GEMM: C[pos][co] = sum_k A[pos][k] * W[co][k] ----------------
// A direct global->reg (all frags hoisted before first barrier), B async LDS (swizzled).
// lda: A row stride (elements). wbs: per-batch W stride (elements, 0 = shared W).
template<int K, int NOUT, int EPI>
__global__ __launch_bounds__(256, 3) void k_gemm(
        const unsigned short* __restrict__ A, const unsigned short* __restrict__ W,
        const void* __restrict__ RES, void* __restrict__ OUT, int lda, int wbs) {
    constexpr int KSTEPS = K / 96;
    static_assert(K % 96 == 0, "K multiple of 96");
    constexpr int SMSH = (KSTEPS > 1) ? 18432 : 12288;   // shorts
    __shared__ unsigned short Bs[SMSH];

    const int t = threadIdx.x;
    const int wv = t >> 6, lane = t & 63;
    const int quad = lane >> 4, lrow = lane & 15;
    const int p0 = blockIdx.x * 128;
    const int co0 = blockIdx.y * 96;
    const unsigned short* Wp = W + (size_t)(p0 >> 16) * wbs;

    f32x4 acc[2][6];
    f32x4 zero = {0.f, 0.f, 0.f, 0.f};
    #pragma unroll
    for (int i = 0; i < 2; i++)
        #pragma unroll
        for (int j = 0; j < 6; j++) acc[i][j] = zero;

    auto stage = [&](int kc, int buf) {
        unsigned short* dst = Bs + buf * 9216;
        const char* Wb = (const char*)Wp;
        #pragma unroll
        for (int j = 0; j < 5; j++) {
            int c = j * 4 + wv;
            if (c < 18) {
                int l = swz(c * 1024 + lane * 16);
                int row = l / 192, cb = l % 192;
                gl2lds16((const unsigned short*)(Wb + ((size_t)(co0 + row) * K + kc * 96) * 2 + cb),
                         dst + c * 512);
            }
        }
    };

    // hoist ALL A-fragments before the first barrier: latency covered by B-stage+drain
    const unsigned short* Arow0 = A + (size_t)(p0 + wv * 32 + lrow) * lda + quad * 8;
    const unsigned short* Arow1 = Arow0 + (size_t)16 * lda;
    bf16x8 a_all[KSTEPS * 3][2];
    #pragma unroll
    for (int kc = 0; kc < KSTEPS; kc++)
        #pragma unroll
        for (int kk = 0; kk < 3; kk++) {
            a_all[kc * 3 + kk][0] = *(const bf16x8*)(Arow0 + kc * 96 + kk * 32);
            a_all[kc * 3 + kk][1] = *(const bf16x8*)(Arow1 + kc * 96 + kk * 32);
        }

    stage(0, 0);
    __syncthreads();
    #pragma unroll
    for (int kc = 0; kc < KSTEPS; kc++) {
        const int cur = kc & 1;
        if (kc + 1 < KSTEPS) stage(kc + 1, cur ^ 1);
        const char* Bp = (const char*)Bs + cur * 18432;
        #pragma unroll
        for (int kk = 0; kk < 3; kk++) {
            bf16x8 bfr[6];
            #pragma unroll
            for (int nt = 0; nt < 6; nt++) {
                int o = swz(((nt * 16 + lrow) * 96 + kk * 32 + quad * 8) * 2);
                bfr[nt] = *(const bf16x8*)(Bp + o);
            }
            #pragma unroll
            for (int mt = 0; mt < 2; mt++)
                #pragma unroll
                for (int nt = 0; nt < 6; nt++)
                    acc[mt][nt] = __builtin_amdgcn_mfma_f32_16x16x32_bf16(a_all[kc * 3 + kk][mt], bfr[nt], acc[mt][nt], 0, 0, 0);
        }
        __syncthreads();
    }

    if (EPI == 0) {
        char* Ds = (char*)Bs;
        #pragma unroll
        for (int mt = 0; mt < 2; mt++)
            #pragma unroll
            for (int nt = 0; nt < 6; nt++)
                #pragma unroll
                for (int r = 0; r < 4; r++) {
                    int o = ((wv * 32 + mt * 16 + quad * 4 + r) * 96 + nt * 16 + lrow) * 2;
                    *(unsigned short*)(Ds + swz(o)) = f2bf(acc[mt][nt][r]);
                }
        __syncthreads();
        unsigned short* o = (unsigned short*)OUT;
        #pragma unroll
        for (int i = 0; i < 6; i++) {
            int g = i * 256 + t;
            int row = g / 12, u = g % 12;
            int so = swz(row * 192 + u * 16);
            *(uint4*)(o + (size_t)(p0 + row) * NOUT + co0 + u * 8) = *(const uint4*)((const char*)Bs + so);
        }
    } else {
        float* o = (float*)OUT;
        #pragma unroll
        for (int mt = 0; mt < 2; mt++)
            #pragma unroll
            for (int nt = 0; nt < 6; nt++)
                #pragma unroll
                for (int r = 0; r < 4; r++) {
                    int m = wv * 32 + mt * 16 + quad * 4 + r;
                    int n = nt * 16 + lrow;
                    size_t idx = (size_t)(p0 + m) * NOUT + co0 + n;
                    float res = (EPI == 1) ? ((const float*)RES)[idx]
                                           : bf2f(((const unsigned short*)RES)[idx]);
                    o[idx] = res + acc[mt][nt][r];
                }
    }
}

// ---------------- attention stats: per-block partial Gram + sq-norms (NO atomics) ----------------
__global__ __launch_bounds__(256) void k_attn_stats(const unsigned short* __restrict__ qkv,
        float* __restrict__ Gpart) {
    __shared__ unsigned short tt[192 * 68];
    const int t = threadIdx.x;
    const int bi = blockIdx.x;
    const int p0 = bi * 256;
    const int cq = t >> 4, ck = t & 15;
    float gacc[6] = {0, 0, 0, 0, 0, 0};
    float nacc = 0.f;
    for (int tl = 0; tl < 4; tl++) {
        const int pb = p0 + tl * 64;
        __syncthreads();
        #pragma unroll
        for (int i = 0; i < 6; i++) {
            int g = i * 256 + t;
            int u = g >> 6, row = g & 63;
            uint4 d = *(const uint4*)(qkv + (size_t)(pb + row) * 288 + u * 8);
            unsigned short v[8];
            *(uint4*)v = d;
            #pragma unroll
            for (int j = 0; j < 8; j++)
                tt[(u * 8 + j) * 68 + row] = v[j];
        }
        __syncthreads();
        #pragma unroll
        for (int hd = 0; hd < 6; hd++) {
            const unsigned short* qp = tt + (hd * 16 + cq) * 68;
            const unsigned short* kp = tt + (96 + hd * 16 + ck) * 68;
            float a = 0.f;
            #pragma unroll
            for (int pg = 0; pg < 16; pg++) {
                ushort4 q4 = *(const ushort4*)(qp + pg * 4);
                ushort4 k4 = *(const ushort4*)(kp + pg * 4);
                a += bf2f(q4.x) * bf2f(k4.x) + bf2f(q4.y) * bf2f(k4.y)
                   + bf2f(q4.z) * bf2f(k4.z) + bf2f(q4.w) * bf2f(k4.w);
            }
            gacc[hd] += a;
        }
        if (t < 192) {
            const unsigned short* cp = tt + t * 68;
            float a = 0.f;
            #pragma unroll
            for (int pg = 0; pg < 16; pg++) {
                ushort4 c4 = *(const ushort4*)(cp + pg * 4);
                a += bf2f(c4.x) * bf2f(c4.x) + bf2f(c4.y) * bf2f(c4.y)
                   + bf2f(c4.z) * bf2f(c4.z) + bf2f(c4.w) * bf2f(c4.w);
            }
            nacc += a;
        }
    }
    float* gp = Gpart + (size_t)bi * 1728;
    #pragma unroll
    for (int hd = 0; hd < 6; hd++) gp[hd * 256 + t] = gacc[hd];
    if (t < 192) gp[1536 + t] = nacc;
}

__global__ __launch_bounds__(256) void k_attn_reduce(const float* __restrict__ Gpart,
        float* __restrict__ G, float* __restrict__ nrm) {
    int idx = blockIdx.x * 256 + threadIdx.x;   // 0..6911
    int b = idx / 1728, j = idx % 1728;
    const float* src = Gpart + (size_t)(b * 256) * 1728 + j;
    float s = 0.f;
    for (int blk = 0; blk < 256; blk++) s += src[(size_t)blk * 1728];
    if (j < 1536) G[b * 1536 + j] = s;
    else nrm[b * 192 + (j - 1536)] = s;
}

// ---------------- softmax over 16-wide rows ----------------
__global__ void k_softmax(const float* __restrict__ G, const float* __restrict__ nrm,
        const float* __restrict__ scale, float* __restrict__ attnW) {
    int t = threadIdx.x; // 384 threads
    int bh = t >> 4, cq = t & 15;
    int b = bh / 6, hd = bh % 6;
    float qn = fmaxf(sqrtf(nrm[b * 192 + hd * 16 + cq]), 1e-12f);
    float l[16];
    float mx = -1e30f;
    #pragma unroll
    for (int ck = 0; ck < 16; ck++) {
        float kn = fmaxf(sqrtf(nrm[b * 192 + 96 + hd * 16 + ck]), 1e-12f);
        float v = G[(bh * 16 + cq) * 16 + ck] / (qn * kn) * scale[hd];
        l[ck] = v; mx = fmaxf(mx, v);
    }
    float s = 0.f;
    #pragma unroll
    for (int ck = 0; ck < 16; ck++) { l[ck] = __expf(l[ck] - mx); s += l[ck]; }
    float inv = 1.f / s;
    #pragma unroll
    for (int ck = 0; ck < 16; ck++) attnW[(bh * 16 + cq) * 16 + ck] = l[ck] * inv;
}

// ---------------- grouped 3x3 dwconv (2ch/group) + gelu gate ----------------
__global__ __launch_bounds__(192) void k_dwgate(const unsigned short* __restrict__ h1,
        const float* __restrict__ dww, unsigned short* __restrict__ out) {
    const int t = threadIdx.x;            // 192
    const int c2 = t % 96, half = t / 96;
    const int pbase = blockIdx.x * 32 + half * 16;   // 16 consecutive positions
    const int h = (pbase >> 8) & 255;                // uniform per block
    const int w0 = pbase & 255;                      // multiple of 16

    float wr[72];
    {
        #pragma unroll
        for (int cb = 0; cb < 4; cb++) {
            int o = (cb & 1) + 2 * c2 + 192 * (cb >> 1);
            const float* src = dww + o * 18;
            #pragma unroll
            for (int k = 0; k < 9; k++) {
                float2 v = *(const float2*)(src + k * 2);
                wr[cb * 18 + k * 2] = v.x;
                wr[cb * 18 + k * 2 + 1] = v.y;
            }
        }
    }

    const bool hv0 = (h > 0), hv2 = (h < 255);
    const unsigned* bp[6];
    #pragma unroll
    for (int dy = 0; dy < 3; dy++) {
        long long rowoff = (long long)(pbase + (dy - 1) * 256) * 192;
        bp[dy * 2 + 0] = (const unsigned*)h1 + rowoff + c2;
        bp[dy * 2 + 1] = (const unsigned*)h1 + rowoff + 96 + c2;
    }
    const bool hvs[3] = { hv0, true, hv2 };

    float win[3][6][2];
    #pragma unroll
    for (int s = 0; s < 6; s++) {
        bool hv = hvs[s >> 1];
        unsigned dl = (hv && w0 > 0) ? bp[s][-1] : 0u;
        unsigned dm = hv ? bp[s][0] : 0u;
        win[0][s][0] = bflo(dl); win[0][s][1] = bfhi(dl);
        win[1][s][0] = bflo(dm); win[1][s][1] = bfhi(dm);
    }

    unsigned* outp = (unsigned*)out + (size_t)pbase * 96 + c2;

    #pragma unroll
    for (int k = 0; k < 16; k++) {
        const bool wv = (w0 + k + 1 < 256);
        #pragma unroll
        for (int s = 0; s < 6; s++) {
            bool hv = hvs[s >> 1];
            unsigned dr = (hv && wv) ? bp[s][k + 1] : 0u;
            win[2][s][0] = bflo(dr); win[2][s][1] = bfhi(dr);
        }
        float a0 = 0.f, a1 = 0.f, a2 = 0.f, a3 = 0.f;
        #pragma unroll
        for (int dy = 0; dy < 3; dy++) {
            #pragma unroll
            for (int dx = 0; dx < 3; dx++) {
                const int tap = dy * 3 + dx;
                float i0 = win[dx][dy * 2][0],     i1 = win[dx][dy * 2][1];
                float i2 = win[dx][dy * 2 + 1][0], i3 = win[dx][dy * 2 + 1][1];
                a0 += wr[tap] * i0      + wr[9 + tap] * i1;
                a1 += wr[18 + tap] * i0 + wr[27 + tap] * i1;
                a2 += wr[36 + tap] * i2 + wr[45 + tap] * i3;
                a3 += wr[54 + tap] * i2 + wr[63 + tap] * i3;
            }
        }
        float g0 = gelu_tanh(a0) * a2;
        float g1 = gelu_tanh(a1) * a3;
        outp[k * 96] = (unsigned)f2bf(g0) | ((unsigned)f2bf(g1) << 16);
        #pragma unroll
        for (int s = 0; s < 6; s++) {
            win[0][s][0] = win[1][s][0]; win[0][s][1] = win[1][s][1];
            win[1][s][0] = win[2][s][0]; win[1][s][1] = win[2][s][1];
        }
    }
}

extern "C" void kernel_launch(void* const* d_in, const int* in_sizes, int n_in,
                              void* d_out, int out_size, void* d_ws, size_t ws_size,
                              hipStream_t stream) {
    const float* x      = (const float*)d_in[0];
    const float* ln1_w  = (const float*)d_in[1];
    const float* ln1_b  = (const float*)d_in[2];
    const float* qkv1_w = (const float*)d_in[3];
    const float* qkv2_w = (const float*)d_in[4];
    const float* proj_w = (const float*)d_in[5];
    const float* scale  = (const float*)d_in[6];
    const float* ln2_w  = (const float*)d_in[7];
    const float* ln2_b  = (const float*)d_in[8];
    const float* pin_w  = (const float*)d_in[9];
    const float* dw_w   = (const float*)d_in[10];
    const float* pout_w = (const float*)d_in[11];
    float* out = (float*)d_out;

    constexpr size_t SZ_WCOMB = (size_t)9 * 288 * 96 * 2;
    constexpr size_t SZ_WPIN  = (size_t)384 * 96 * 2;
    constexpr size_t SZ_WPOUT = (size_t)96 * 192 * 2;
    constexpr size_t SZ_WB    = (size_t)4 * 96 * 96 * 2;
    constexpr size_t SZ_STATS = (size_t)13056 * 4;
    constexpr size_t SZ_APAD  = (size_t)4 * 256 * 258 * 96 * 2;   // padded y1 slot, 48.4 MB
    constexpr size_t SZ_XRES  = (size_t)NPOS * 96 * 2;            // 48 MB
    constexpr size_t SZ_B = (size_t)NPOS * 288 * 2;               // 144 MB
    constexpr size_t SZ_C = (size_t)NPOS * 96 * 4;                // 96 MB
    constexpr size_t OFF_WCOMB = 0;
    constexpr size_t OFF_WPIN  = OFF_WCOMB + SZ_WCOMB;
    constexpr size_t OFF_WPOUT = OFF_WPIN + SZ_WPIN;
    constexpr size_t OFF_WB    = OFF_WPOUT + SZ_WPOUT;
    constexpr size_t OFF_STATS = OFF_WB + SZ_WB;
    constexpr size_t OFF_A = OFF_STATS + SZ_STATS;
    constexpr size_t OFF_B = OFF_A + SZ_APAD;
    constexpr size_t OFF_C = OFF_B + SZ_B;
    constexpr size_t NEED = OFF_C + SZ_C;

    if (ws_size < NEED) {
        k_fillz<<<(out_size + 255) / 256, 256, 0, stream>>>(out, out_size);
        return;
    }

    char* ws = (char*)d_ws;
    unsigned short* Wcomb = (unsigned short*)(ws + OFF_WCOMB);
    unsigned short* Wpin  = (unsigned short*)(ws + OFF_WPIN);
    unsigned short* Wpout = (unsigned short*)(ws + OFF_WPOUT);
    unsigned short* Wb    = (unsigned short*)(ws + OFF_WB);
    float* stats = (float*)(ws + OFF_STATS);
    float* G     = stats;
    float* nrm   = stats + 6144;
    float* attnW = stats + 6912;

    unsigned short* y1p      = (unsigned short*)(ws + OFF_A);     // padded [4][256][258][96]
    unsigned short* qkv      = (unsigned short*)(ws + OFF_B);
    unsigned short* xres     = (unsigned short*)(ws + OFF_C);
    unsigned short* y2       = (unsigned short*)(ws + OFF_C + SZ_XRES);
    float*          Gpart    = (float*)(ws + OFF_C + SZ_XRES);
    unsigned short* h1       = (unsigned short*)(ws + OFF_A);     // 192 MB, fits in [OFF_A, OFF_C)
    unsigned short* gated    = (unsigned short*)(ws + OFF_C);
    float*          Fout     = (float*)(ws + OFF_A);
    float* x2 = out;

    // weight prep + pad fill
    k_combine_qkv<<<9 * 288, 96, 0, stream>>>(qkv2_w, qkv1_w, Wcomb);
    k_f32_to_bf16<<<(384 * 96 + 255) / 256, 256, 0, stream>>>(pin_w, Wpin, 384 * 96);
    k_f32_to_bf16<<<(96 * 192 + 255) / 256, 256, 0, stream>>>(pout_w, Wpout, 96 * 192);
    k_fillpad<<<384, 256, 0, stream>>>((unsigned*)y1p);

    // LN1 (+ NCHW->NHWC padded), residual snapshot
    k_ln1<<<NPOS / 64, 256, 0, stream>>>(x, ln1_w, ln1_b, xres, y1p);
    // combined qkv conv: 3x3, 96 -> 288 (barrier-free, B from L2)
    k_qkvconv<<<dim3(3, 2048), 256, 0, stream>>>(y1p, Wcomb, qkv);
    // attention stats + softmax
    k_attn_stats<<<NPOS / 256, 256, 0, stream>>>(qkv, Gpart);
    k_attn_reduce<<<27, 256, 0, stream>>>(Gpart, G, nrm);
    k_softmax<<<1, 384, 0, stream>>>(G, nrm, scale, attnW);
    // fold apply+proj: per-batch combined weight Wb = blockdiag(aw)^T * Wproj^T
    k_combine_wb<<<4 * 96, 96, 0, stream>>>(proj_w, attnW, Wb);
    // proj directly on V slice of qkv (lda=288, per-batch W) + residual(bf16) -> x2
    k_gemm<96, 96, 2><<<dim3(2048, 1), 256, 0, stream>>>(qkv + 192, Wb, xres, x2, 288, 9216);
    // LN2
    k_ln2<<<NPOS / 64, 256, 0, stream>>>(x2, ln2_w, ln2_b, y2);
    // pin: 96 -> 384
    k_gemm<96, 384, 0><<<dim3(2048, 4), 256, 0, stream>>>(y2, Wpin, nullptr, h1, 96, 0);
    // grouped 3x3 + gelu gate
    k_dwgate<<<NPOS / 32, 192, 0, stream>>>(h1, dw_w, gated);
    // pout + residual(fp32) -> Fout
    k_gemm<192, 96, 1><<<dim3(2048, 1), 256, 0, stream>>>(gated, Wpout, x2, Fout, 192, 0);
    // NHWC -> NCHW final
    k_tout<<<NPOS / 64, 256, 0, stream>>>(Fout, out);
}

// Round 5
// 899.861 us; speedup vs baseline: 1.0646x; 1.0646x over previous
//
#include <hip/hip_runtime.h>
#include <hip/hip_bf16.h>

#define NPOS 262144   // 4 * 256 * 256

typedef short bf16x8 __attribute__((ext_vector_type(8)));
typedef float f32x4 __attribute__((ext_vector_type(4)));

__device__ __forceinline__ unsigned short f2bf(float f) {
    union { float f; unsigned u; } v; v.f = f;
    unsigned r = v.u + 0x7fffu + ((v.u >> 16) & 1u);
    return (unsigned short)(r >> 16);
}
__device__ __forceinline__ float bf2f(unsigned short h) {
    union { unsigned u; float f; } v; v.u = ((unsigned)h) << 16;
    return v.f;
}
__device__ __forceinline__ float bflo(unsigned d) {
    union { unsigned u; float f; } v; v.u = d << 16;
    return v.f;
}
__device__ __forceinline__ float bfhi(unsigned d) {
    union { unsigned u; float f; } v; v.u = d & 0xffff0000u;
    return v.f;
}
__device__ __forceinline__ float gelu_tanh(float x) {
    float u = 0.7978845608028654f * (x + 0.044715f * x * x * x);
    float t = 1.0f - 2.0f / (__expf(2.0f * u) + 1.0f);
    return 0.5f * x * (1.0f + t);
}
// XOR bank swizzle: involution, flips byte-addr bits [6:4] with bits [9:7].
__device__ __forceinline__ int swz(int o) {
    return o ^ (((o >> 7) & 7) << 4);
}

// async global -> LDS, 16B per lane. LDS dest is wave-uniform base + lane*16.
__device__ __forceinline__ void gl2lds16(const unsigned short* __restrict__ g, unsigned short* l) {
    __builtin_amdgcn_global_load_lds(
        (const __attribute__((address_space(1))) unsigned int*)(const void*)g,
        (__attribute__((address_space(3))) unsigned int*)(void*)l,
        16, 0, 0);
}

// ---------------- utility ----------------
__global__ void k_fillz(float* __restrict__ p, int n) {
    int i = blockIdx.x * 256 + threadIdx.x;
    if (i < n) p[i] = 0.f;
}
__global__ void k_f32_to_bf16(const float* __restrict__ src, unsigned short* __restrict__ dst, int n) {
    int i = blockIdx.x * 256 + threadIdx.x;
    if (i < n) dst[i] = f2bf(src[i]);
}

// zero the two pad columns (wp=0, wp=257) of the padded y1 buffer [4][256][258][96]
__global__ void k_fillpad(unsigned* __restrict__ y1p32) {
    int i = blockIdx.x * 256 + threadIdx.x;   // < 98304 = 1024*2*48
    if (i >= 98304) return;
    int pos = i / 48, c2 = i % 48;
    int bh = pos >> 1, side = pos & 1;
    size_t o = ((size_t)bh * 258 + (size_t)side * 257) * 48 + c2;
    y1p32[o] = 0u;
}

// Combined qkv weight: Wc[tap][co][ci] = sum_k w2[co][k][tap] * w1[k][ci]
__global__ void k_combine_qkv(const float* __restrict__ w2, const float* __restrict__ w1,
        unsigned short* __restrict__ out) {
    int bx = blockIdx.x;           // 9*288
    int tap = bx / 288, co = bx % 288;
    int ci = threadIdx.x;          // 96
    const float* w2p = w2 + (size_t)co * 2592 + tap;
    float acc = 0.f;
    for (int k = 0; k < 288; k++)
        acc += w2p[k * 9] * w1[k * 96 + ci];
    out[((size_t)tap * 288 + co) * 96 + ci] = f2bf(acc);
}

// Combined apply+proj weight: Wb[b][n][m] = sum_j proj_w[n][hd(m)*16+j] * attnW[b][hd(m)*16+j][ck(m)]
__global__ void k_combine_wb(const float* __restrict__ proj_w, const float* __restrict__ attnW,
        unsigned short* __restrict__ Wb) {
    int bx = blockIdx.x;          // 4*96
    int b = bx / 96, n = bx % 96;
    int m = threadIdx.x;          // 96
    int hd = m >> 4, ck = m & 15;
    float acc = 0.f;
    #pragma unroll
    for (int j = 0; j < 16; j++)
        acc += proj_w[n * 96 + hd * 16 + j] * attnW[(size_t)b * 1536 + (hd * 16 + j) * 16 + ck];
    Wb[((size_t)b * 96 + n) * 96 + m] = f2bf(acc);
}

// ---------------- LN1: NCHW fp32 -> xres (NHWC bf16) + y1p (padded NHWC bf16) ----------------
__global__ __launch_bounds__(256) void k_ln1(const float* __restrict__ x,
        const float* __restrict__ lnw, const float* __restrict__ lnb,
        unsigned short* __restrict__ xres, unsigned short* __restrict__ y1p) {
    __shared__ float tile[96 * 65];
    __shared__ float smu[64], srs[64];
    const int t = threadIdx.x;
    const int p0 = blockIdx.x * 64;
    const int b = p0 >> 16, hw0 = p0 & 65535;
    const int h = hw0 >> 8, w0 = hw0 & 255;
    const size_t padbase = ((size_t)(b * 256 + h) * 258 + (w0 + 1)) * 96;
    #pragma unroll
    for (int i = 0; i < 24; i++) {
        int g = i * 256 + t;
        int c = g >> 6, pos = g & 63;
        tile[c * 65 + pos] = x[(size_t)(b * 96 + c) * 65536 + hw0 + pos];
    }
    __syncthreads();
    if (t < 64) {
        float s = 0.f, s2 = 0.f;
        for (int c = 0; c < 96; c++) { float v = tile[c * 65 + t]; s += v; s2 += v * v; }
        float mu = s * (1.0f / 96.0f);
        float var = s2 * (1.0f / 96.0f) - mu * mu;
        smu[t] = mu; srs[t] = rsqrtf(var + 1e-5f);
    }
    __syncthreads();
    #pragma unroll
    for (int i = 0; i < 12; i++) {
        int g2 = (i * 256 + t) * 2;
        int pos = g2 / 96, c = g2 % 96;
        float v0 = tile[c * 65 + pos], v1 = tile[(c + 1) * 65 + pos];
        float mu = smu[pos], rs = srs[pos];
        size_t o = (size_t)(p0 + pos) * 96 + c;
        *(unsigned*)(xres + o) = (unsigned)f2bf(v0) | ((unsigned)f2bf(v1) << 16);
        unsigned short a0 = f2bf((v0 - mu) * rs * lnw[c] + lnb[c]);
        unsigned short a1 = f2bf((v1 - mu) * rs * lnw[c + 1] + lnb[c + 1]);
        *(unsigned*)(y1p + padbase + (size_t)pos * 96 + c) = (unsigned)a0 | ((unsigned)a1 << 16);
    }
}

// ---------------- LN2: NCHW fp32 (d_out) -> NHWC bf16 ----------------
__global__ __launch_bounds__(256) void k_ln2n(const float* __restrict__ x,
        const float* __restrict__ lnw, const float* __restrict__ lnb,
        unsigned short* __restrict__ y2) {
    __shared__ float tile[96 * 65];
    __shared__ float smu[64], srs[64];
    const int t = threadIdx.x;
    const int p0 = blockIdx.x * 64;
    const int b = p0 >> 16, hw0 = p0 & 65535;
    #pragma unroll
    for (int i = 0; i < 24; i++) {
        int g = i * 256 + t;
        int c = g >> 6, pos = g & 63;
        tile[c * 65 + pos] = x[(size_t)(b * 96 + c) * 65536 + hw0 + pos];
    }
    __syncthreads();
    if (t < 64) {
        float s = 0.f, s2 = 0.f;
        for (int c = 0; c < 96; c++) { float v = tile[c * 65 + t]; s += v; s2 += v * v; }
        float mu = s * (1.0f / 96.0f);
        float var = s2 * (1.0f / 96.0f) - mu * mu;
        smu[t] = mu; srs[t] = rsqrtf(var + 1e-5f);
    }
    __syncthreads();
    #pragma unroll
    for (int i = 0; i < 12; i++) {
        int g2 = (i * 256 + t) * 2;
        int pos = g2 / 96, c = g2 % 96;
        float mu = smu[pos], rs = srs[pos];
        unsigned short a0 = f2bf((tile[c * 65 + pos] - mu) * rs * lnw[c] + lnb[c]);
        unsigned short a1 = f2bf((tile[(c + 1) * 65 + pos] - mu) * rs * lnw[c + 1] + lnb[c + 1]);
        *(unsigned*)(y2 + (size_t)p0 * 96 + g2) = (unsigned)a0 | ((unsigned)a1 << 16);
    }
}

// ---------------- qkv 3x3 conv as pipelined MFMA GEMM (counted vmcnt) ----------------
// A: padded y1 [4][256][258][96] bf16, direct global->reg per kk.
// B: Wcomb [9][288][96] bf16, double-buffered LDS via global_load_lds (swizzled).
// Per tap: issue next stage (5 chunks/wave, uniform) -> s_waitcnt vmcnt(5)
// (own current-tap chunks done; next-tap loads stay in flight across the
// barrier) -> raw s_barrier -> MFMA -> raw s_barrier. No vmcnt(0) drain.
__global__ __launch_bounds__(256, 4) void k_qkvconv(
        const unsigned short* __restrict__ Ap,
        const unsigned short* __restrict__ W,
        unsigned short* __restrict__ OUT) {
    __shared__ unsigned short Bs[2][10240];   // 2 x 20KB (18KB tap + 2KB slack for uniform 20-chunk stage)
    const int t = threadIdx.x;
    const int wv = t >> 6, lane = t & 63;
    const int wr = wv >> 1, wc = wv & 1;
    const int quad = lane >> 4, lrow = lane & 15;

    // bijective XCD swizzle: 6144 blocks, 8 XCDs, 768/chunk
    const int lin = blockIdx.y * 3 + blockIdx.x;
    const int sw = (lin & 7) * 768 + (lin >> 3);
    const int co0 = (sw % 3) * 96;
    const int p0 = (sw / 3) * 128;

    const int b = p0 >> 16;
    const int hw0 = p0 & 65535;
    const int h = hw0 >> 8, w0 = hw0 & 255;

    const int tfirst = (h == 0) ? 3 : 0;
    const int nv = (h == 0 || h == 255) ? 6 : 9;

    // A row pointers (center tap): rows wr*64+lrow and wr*64+32+lrow
    const unsigned short* arowA;
    {
        const size_t base = ((size_t)(b * 256 + h) * 258 + (w0 + 1)) * 96;
        arowA = Ap + base + (size_t)(wr * 64 + lrow) * 96 + quad * 8;
    }
    const unsigned short* arowB = arowA + 32 * 96;

    // precomputed swizzled B read offsets (loop-invariant)
    int boff[3][3];
    #pragma unroll
    for (int kk = 0; kk < 3; kk++)
        #pragma unroll
        for (int nt = 0; nt < 3; nt++)
            boff[kk][nt] = swz(((wc * 48 + nt * 16 + lrow) * 96 + kk * 32 + quad * 8) * 2);

    f32x4 acc[4][3];
    f32x4 zero = {0.f, 0.f, 0.f, 0.f};
    #pragma unroll
    for (int i = 0; i < 4; i++)
        #pragma unroll
        for (int j = 0; j < 3; j++) acc[i][j] = zero;

    auto stage = [&](int tp, int buf) {
        const char* Wt = (const char*)(W + (size_t)(tp * 288 + co0) * 96);
        unsigned short* dst = (unsigned short*)Bs + buf * 10240;
        #pragma unroll
        for (int j = 0; j < 5; j++) {
            int c = j * 4 + wv;               // 0..19, exactly 5 chunks per wave
            int l = c * 1024 + lane * 16;
            gl2lds16((const unsigned short*)(Wt + swz(l)), dst + c * 512);
        }
    };

    stage(tfirst, 0);

    int cur = 0;
    for (int i = 0; i < nv; i++) {
        const int tp = tfirst + i;
        const int doff = ((tp / 3) - 1) * (258 * 96) + ((tp % 3) - 1) * 96;
        if (i + 1 < nv) {
            stage(tp + 1, cur ^ 1);
            // own 5 newest (next-tap) loads may stay in flight; all older (this tap) retired
            asm volatile("s_waitcnt vmcnt(5)" ::: "memory");
        } else {
            asm volatile("s_waitcnt vmcnt(0)" ::: "memory");
        }
        __builtin_amdgcn_s_barrier();    // all waves' current-tap chunks in LDS
        const unsigned short* pA = arowA + doff;
        const unsigned short* pB = arowB + doff;
        const char* Bp = (const char*)Bs + cur * 20480;
        #pragma unroll
        for (int kk = 0; kk < 3; kk++) {
            bf16x8 a[4], bb[3];
            a[0] = *(const bf16x8*)(pA + kk * 32);
            a[1] = *(const bf16x8*)(pA + 1536 + kk * 32);
            a[2] = *(const bf16x8*)(pB + kk * 32);
            a[3] = *(const bf16x8*)(pB + 1536 + kk * 32);
            #pragma unroll
            for (int nt = 0; nt < 3; nt++)
                bb[nt] = *(const bf16x8*)(Bp + boff[kk][nt]);
            #pragma unroll
            for (int mt = 0; mt < 4; mt++)
                #pragma unroll
                for (int nt = 0; nt < 3; nt++)
                    acc[mt][nt] = __builtin_amdgcn_mfma_f32_16x16x32_bf16(a[mt], bb[nt], acc[mt][nt], 0, 0, 0);
        }
        __builtin_amdgcn_s_barrier();    // reads done before next iter's stage overwrites
        cur ^= 1;
    }

    // epilogue: stage 128x96 bf16 through LDS (swizzled), vectorized store
    char* Dp = (char*)Bs;
    #pragma unroll
    for (int mt = 0; mt < 4; mt++)
        #pragma unroll
        for (int nt = 0; nt < 3; nt++)
            #pragma unroll
            for (int r = 0; r < 4; r++) {
                int o = ((wr * 64 + mt * 16 + quad * 4 + r) * 96 + wc * 48 + nt * 16 + lrow) * 2;
                *(unsigned short*)(Dp + swz(o)) = f2bf(acc[mt][nt][r]);
            }
    __syncthreads();
    #pragma unroll
    for (int i = 0; i < 6; i++) {
        int g = i * 256 + t;
        int row = g / 12, u = g % 12;
        int o = swz(row * 192 + u * 16);
        *(uint4*)(OUT + (size_t)(p0 + row) * 288 + co0 + u * 8) = *(const uint4*)(Dp + o);
    }
}

// ---------------- generic 1x1 MFMA GEMM: C[pos][co] = sum_k A[pos][k] * W[co][k] ----------------
// A direct global->reg (all frags hoisted before first barrier), B async LDS (swizzled).
// EPI 0: bf16 NHWC out. EPI 1: fp32 NCHW out += NCHW fp32 res (in-place RMW safe).
// EPI 2: fp32 NCHW out, res = NHWC bf16 added pre-transpose.
// lda: A row stride (elements). wbs: per-batch W stride (elements, 0 = shared W).
template<int K, int NOUT, int EPI>
__global__ __launch_bounds__(256, 3) void k_gemm(
        const unsigned short* __restrict__ A, const unsigned short* __restrict__ W,
        const void* RES, void* OUT, int lda, int wbs) {
    constexpr int KSTEPS = K / 96;
    static_assert(K % 96 == 0, "K multiple of 96");
    constexpr int STB = (KSTEPS > 1) ? 36864 : 18432;       // staging bytes
    constexpr int EPB = (EPI == 0) ? 24576 : 24832;          // epilogue bytes
    constexpr int SMB = STB > EPB ? STB : EPB;
    __shared__ __align__(16) char smem[SMB];
    unsigned short* Bs = (unsigned short*)smem;

    const int t = threadIdx.x;
    const int wv = t >> 6, lane = t & 63;
    const int quad = lane >> 4, lrow = lane & 15;
    const int p0 = blockIdx.x * 128;
    const int co0 = blockIdx.y * 96;
    const unsigned short* Wp = W + (size_t)(p0 >> 16) * wbs;

    f32x4 acc[2][6];
    f32x4 zero = {0.f, 0.f, 0.f, 0.f};
    #pragma unroll
    for (int i = 0; i < 2; i++)
        #pragma unroll
        for (int j = 0; j < 6; j++) acc[i][j] = zero;

    auto stage = [&](int kc, int buf) {
        unsigned short* dst = Bs + buf * 9216;
        const char* Wb = (const char*)Wp;
        #pragma unroll
        for (int j = 0; j < 5; j++) {
            int c = j * 4 + wv;
            if (c < 18) {
                int l = swz(c * 1024 + lane * 16);
                int row = l / 192, cb = l % 192;
                gl2lds16((const unsigned short*)(Wb + ((size_t)(co0 + row) * K + kc * 96) * 2 + cb),
                         dst + c * 512);
            }
        }
    };

    // hoist ALL A-fragments before the first barrier: latency covered by B-stage+drain
    const unsigned short* Arow0 = A + (size_t)(p0 + wv * 32 + lrow) * lda + quad * 8;
    const unsigned short* Arow1 = Arow0 + (size_t)16 * lda;
    bf16x8 a_all[KSTEPS * 3][2];
    #pragma unroll
    for (int kc = 0; kc < KSTEPS; kc++)
        #pragma unroll
        for (int kk = 0; kk < 3; kk++) {
            a_all[kc * 3 + kk][0] = *(const bf16x8*)(Arow0 + kc * 96 + kk * 32);
            a_all[kc * 3 + kk][1] = *(const bf16x8*)(Arow1 + kc * 96 + kk * 32);
        }

    stage(0, 0);
    __syncthreads();
    #pragma unroll
    for (int kc = 0; kc < KSTEPS; kc++) {
        const int cur = kc & 1;
        if (kc + 1 < KSTEPS) stage(kc + 1, cur ^ 1);
        const char* Bp = (const char*)smem + cur * 18432;
        #pragma unroll
        for (int kk = 0; kk < 3; kk++) {
            bf16x8 bfr[6];
            #pragma unroll
            for (int nt = 0; nt < 6; nt++) {
                int o = swz(((nt * 16 + lrow) * 96 + kk * 32 + quad * 8) * 2);
                bfr[nt] = *(const bf16x8*)(Bp + o);
            }
            #pragma unroll
            for (int mt = 0; mt < 2; mt++)
                #pragma unroll
                for (int nt = 0; nt < 6; nt++)
                    acc[mt][nt] = __builtin_amdgcn_mfma_f32_16x16x32_bf16(a_all[kc * 3 + kk][mt], bfr[nt], acc[mt][nt], 0, 0, 0);
        }
        __syncthreads();
    }

    if (EPI == 0) {
        char* Ds = (char*)smem;
        #pragma unroll
        for (int mt = 0; mt < 2; mt++)
            #pragma unroll
            for (int nt = 0; nt < 6; nt++)
                #pragma unroll
                for (int r = 0; r < 4; r++) {
                    int o = ((wv * 32 + mt * 16 + quad * 4 + r) * 96 + nt * 16 + lrow) * 2;
                    *(unsigned short*)(Ds + swz(o)) = f2bf(acc[mt][nt][r]);
                }
        __syncthreads();
        unsigned short* o = (unsigned short*)OUT;
        #pragma unroll
        for (int i = 0; i < 6; i++) {
            int g = i * 256 + t;
            int row = g / 12, u = g % 12;
            int so = swz(row * 192 + u * 16);
            *(uint4*)(o + (size_t)(p0 + row) * NOUT + co0 + u * 8) = *(const uint4*)((const char*)smem + so);
        }
    } else {
        // NCHW fp32 output via LDS f32 transpose (stride-97 rows, 2 half passes)
        if (EPI == 2) {
            const unsigned short* R = (const unsigned short*)RES;
            #pragma unroll
            for (int mt = 0; mt < 2; mt++)
                #pragma unroll
                for (int nt = 0; nt < 6; nt++)
                    #pragma unroll
                    for (int r = 0; r < 4; r++) {
                        int m = wv * 32 + mt * 16 + quad * 4 + r;
                        int n = nt * 16 + lrow;
                        acc[mt][nt][r] += bf2f(R[(size_t)(p0 + m) * 96 + n]);
                    }
        }
        const int b = p0 >> 16, hw0 = p0 & 65535;
        float* T = (float*)smem;
        const float* RESf = (const float*)RES;
        float* OUTf = (float*)OUT;
        #pragma unroll
        for (int pass = 0; pass < 2; pass++) {
            __syncthreads();
            if ((wv >> 1) == pass) {
                #pragma unroll
                for (int mt = 0; mt < 2; mt++)
                    #pragma unroll
                    for (int nt = 0; nt < 6; nt++)
                        #pragma unroll
                        for (int r = 0; r < 4; r++) {
                            int lm = (wv & 1) * 32 + mt * 16 + quad * 4 + r;
                            T[lm * 97 + nt * 16 + lrow] = acc[mt][nt][r];
                        }
            }
            __syncthreads();
            #pragma unroll
            for (int i = 0; i < 24; i++) {
                int g = i * 256 + t;
                int c = g >> 6, lm = g & 63;
                float v = T[lm * 97 + c];
                size_t o = (size_t)(b * 96 + c) * 65536 + hw0 + pass * 64 + lm;
                if (EPI == 1) v += RESf[o];
                OUTf[o] = v;
            }
        }
    }
}

// ---------------- attention stats: per-block partial Gram + sq-norms (NO atomics) ----------------
__global__ __launch_bounds__(256) void k_attn_stats(const unsigned short* __restrict__ qkv,
        float* __restrict__ Gpart) {
    __shared__ unsigned short tt[192 * 68];
    const int t = threadIdx.x;
    const int bi = blockIdx.x;
    const int p0 = bi * 256;
    const int cq = t >> 4, ck = t & 15;
    float gacc[6] = {0, 0, 0, 0, 0, 0};
    float nacc = 0.f;
    for (int tl = 0; tl < 4; tl++) {
        const int pb = p0 + tl * 64;
        __syncthreads();
        #pragma unroll
        for (int i = 0; i < 6; i++) {
            int g = i * 256 + t;
            int u = g >> 6, row = g & 63;
            uint4 d = *(const uint4*)(qkv + (size_t)(pb + row) * 288 + u * 8);
            unsigned short v[8];
            *(uint4*)v = d;
            #pragma unroll
            for (int j = 0; j < 8; j++)
                tt[(u * 8 + j) * 68 + row] = v[j];
        }
        __syncthreads();
        #pragma unroll
        for (int hd = 0; hd < 6; hd++) {
            const unsigned short* qp = tt + (hd * 16 + cq) * 68;
            const unsigned short* kp = tt + (96 + hd * 16 + ck) * 68;
            float a = 0.f;
            #pragma unroll
            for (int pg = 0; pg < 16; pg++) {
                ushort4 q4 = *(const ushort4*)(qp + pg * 4);
                ushort4 k4 = *(const ushort4*)(kp + pg * 4);
                a += bf2f(q4.x) * bf2f(k4.x) + bf2f(q4.y) * bf2f(k4.y)
                   + bf2f(q4.z) * bf2f(k4.z) + bf2f(q4.w) * bf2f(k4.w);
            }
            gacc[hd] += a;
        }
        if (t < 192) {
            const unsigned short* cp = tt + t * 68;
            float a = 0.f;
            #pragma unroll
            for (int pg = 0; pg < 16; pg++) {
                ushort4 c4 = *(const ushort4*)(cp + pg * 4);
                a += bf2f(c4.x) * bf2f(c4.x) + bf2f(c4.y) * bf2f(c4.y)
                   + bf2f(c4.z) * bf2f(c4.z) + bf2f(c4.w) * bf2f(c4.w);
            }
            nacc += a;
        }
    }
    float* gp = Gpart + (size_t)bi * 1728;
    #pragma unroll
    for (int hd = 0; hd < 6; hd++) gp[hd * 256 + t] = gacc[hd];
    if (t < 192) gp[1536 + t] = nacc;
}

__global__ __launch_bounds__(256) void k_attn_reduce(const float* __restrict__ Gpart,
        float* __restrict__ G, float* __restrict__ nrm) {
    int idx = blockIdx.x * 256 + threadIdx.x;   // 0..6911
    int b = idx / 1728, j = idx % 1728;
    const float* src = Gpart + (size_t)(b * 256) * 1728 + j;
    float s = 0.f;
    for (int blk = 0; blk < 256; blk++) s += src[(size_t)blk * 1728];
    if (j < 1536) G[b * 1536 + j] = s;
    else nrm[b * 192 + (j - 1536)] = s;
}

// ---------------- softmax over 16-wide rows ----------------
__global__ void k_softmax(const float* __restrict__ G, const float* __restrict__ nrm,
        const float* __restrict__ scale, float* __restrict__ attnW) {
    int t = threadIdx.x; // 384 threads
    int bh = t >> 4, cq = t & 15;
    int b = bh / 6, hd = bh % 6;
    float qn = fmaxf(sqrtf(nrm[b * 192 + hd * 16 + cq]), 1e-12f);
    float l[16];
    float mx = -1e30f;
    #pragma unroll
    for (int ck = 0; ck < 16; ck++) {
        float kn = fmaxf(sqrtf(nrm[b * 192 + 96 + hd * 16 + ck]), 1e-12f);
        float v = G[(bh * 16 + cq) * 16 + ck] / (qn * kn) * scale[hd];
        l[ck] = v; mx = fmaxf(mx, v);
    }
    float s = 0.f;
    #pragma unroll
    for (int ck = 0; ck < 16; ck++) { l[ck] = __expf(l[ck] - mx); s += l[ck]; }
    float inv = 1.f / s;
    #pragma unroll
    for (int ck = 0; ck < 16; ck++) attnW[(bh * 16 + cq) * 16 + ck] = l[ck] * inv;
}

// ---------------- grouped 3x3 dwconv (2ch/group) + gelu gate ----------------
__global__ __launch_bounds__(192) void k_dwgate(const unsigned short* __restrict__ h1,
        const float* __restrict__ dww, unsigned short* __restrict__ out) {
    const int t = threadIdx.x;            // 192
    const int c2 = t % 96, half = t / 96;
    const int pbase = blockIdx.x * 32 + half * 16;   // 16 consecutive positions
    const int h = (pbase >> 8) & 255;                // uniform per block
    const int w0 = pbase & 255;                      // multiple of 16

    float wr[72];
    {
        #pragma unroll
        for (int cb = 0; cb < 4; cb++) {
            int o = (cb & 1) + 2 * c2 + 192 * (cb >> 1);
            const float* src = dww + o * 18;
            #pragma unroll
            for (int k = 0; k < 9; k++) {
                float2 v = *(const float2*)(src + k * 2);
                wr[cb * 18 + k * 2] = v.x;
                wr[cb * 18 + k * 2 + 1] = v.y;
            }
        }
    }

    const bool hv0 = (h > 0), hv2 = (h < 255);
    const unsigned* bp[6];
    #pragma unroll
    for (int dy = 0; dy < 3; dy++) {
        long long rowoff = (long long)(pbase + (dy - 1) * 256) * 192;
        bp[dy * 2 + 0] = (const unsigned*)h1 + rowoff + c2;
        bp[dy * 2 + 1] = (const unsigned*)h1 + rowoff + 96 + c2;
    }
    const bool hvs[3] = { hv0, true, hv2 };

    float win[3][6][2];
    #pragma unroll
    for (int s = 0; s < 6; s++) {
        bool hv = hvs[s >> 1];
        unsigned dl = (hv && w0 > 0) ? bp[s][-1] : 0u;
        unsigned dm = hv ? bp[s][0] : 0u;
        win[0][s][0] = bflo(dl); win[0][s][1] = bfhi(dl);
        win[1][s][0] = bflo(dm); win[1][s][1] = bfhi(dm);
    }

    unsigned* outp = (unsigned*)out + (size_t)pbase * 96 + c2;

    #pragma unroll
    for (int k = 0; k < 16; k++) {
        const bool wv = (w0 + k + 1 < 256);
        #pragma unroll
        for (int s = 0; s < 6; s++) {
            bool hv = hvs[s >> 1];
            unsigned dr = (hv && wv) ? bp[s][k + 1] : 0u;
            win[2][s][0] = bflo(dr); win[2][s][1] = bfhi(dr);
        }
        float a0 = 0.f, a1 = 0.f, a2 = 0.f, a3 = 0.f;
        #pragma unroll
        for (int dy = 0; dy < 3; dy++) {
            #pragma unroll
            for (int dx = 0; dx < 3; dx++) {
                const int tap = dy * 3 + dx;
                float i0 = win[dx][dy * 2][0],     i1 = win[dx][dy * 2][1];
                float i2 = win[dx][dy * 2 + 1][0], i3 = win[dx][dy * 2 + 1][1];
                a0 += wr[tap] * i0      + wr[9 + tap] * i1;
                a1 += wr[18 + tap] * i0 + wr[27 + tap] * i1;
                a2 += wr[36 + tap] * i2 + wr[45 + tap] * i3;
                a3 += wr[54 + tap] * i2 + wr[63 + tap] * i3;
            }
        }
        float g0 = gelu_tanh(a0) * a2;
        float g1 = gelu_tanh(a1) * a3;
        outp[k * 96] = (unsigned)f2bf(g0) | ((unsigned)f2bf(g1) << 16);
        #pragma unroll
        for (int s = 0; s < 6; s++) {
            win[0][s][0] = win[1][s][0]; win[0][s][1] = win[1][s][1];
            win[1][s][0] = win[2][s][0]; win[1][s][1] = win[2][s][1];
        }
    }
}

extern "C" void kernel_launch(void* const* d_in, const int* in_sizes, int n_in,
                              void* d_out, int out_size, void* d_ws, size_t ws_size,
                              hipStream_t stream) {
    const float* x      = (const float*)d_in[0];
    const float* ln1_w  = (const float*)d_in[1];
    const float* ln1_b  = (const float*)d_in[2];
    const float* qkv1_w = (const float*)d_in[3];
    const float* qkv2_w = (const float*)d_in[4];
    const float* proj_w = (const float*)d_in[5];
    const float* scale  = (const float*)d_in[6];
    const float* ln2_w  = (const float*)d_in[7];
    const float* ln2_b  = (const float*)d_in[8];
    const float* pin_w  = (const float*)d_in[9];
    const float* dw_w   = (const float*)d_in[10];
    const float* pout_w = (const float*)d_in[11];
    float* out = (float*)d_out;

    constexpr size_t SZ_WCOMB = (size_t)9 * 288 * 96 * 2 + 4096;  // +slack for uniform 20-chunk stage
    constexpr size_t SZ_WPIN  = (size_t)384 * 96 * 2;
    constexpr size_t SZ_WPOUT = (size_t)96 * 192 * 2;
    constexpr size_t SZ_WB    = (size_t)4 * 96 * 96 * 2;
    constexpr size_t SZ_STATS = (size_t)13056 * 4;
    constexpr size_t SZ_APAD  = (size_t)4 * 256 * 258 * 96 * 2;   // padded y1 slot, 48.4 MB
    constexpr size_t SZ_XRES  = (size_t)NPOS * 96 * 2;            // 48 MB
    constexpr size_t SZ_B = (size_t)NPOS * 288 * 2;               // 144 MB
    constexpr size_t SZ_C = (size_t)NPOS * 96 * 4;                // 96 MB
    constexpr size_t OFF_WCOMB = 0;
    constexpr size_t OFF_WPIN  = OFF_WCOMB + SZ_WCOMB;
    constexpr size_t OFF_WPOUT = OFF_WPIN + SZ_WPIN;
    constexpr size_t OFF_WB    = OFF_WPOUT + SZ_WPOUT;
    constexpr size_t OFF_STATS = OFF_WB + SZ_WB;
    constexpr size_t OFF_A = OFF_STATS + SZ_STATS;
    constexpr size_t OFF_B = OFF_A + SZ_APAD;
    constexpr size_t OFF_C = OFF_B + SZ_B;
    constexpr size_t NEED = OFF_C + SZ_C;

    if (ws_size < NEED) {
        k_fillz<<<(out_size + 255) / 256, 256, 0, stream>>>(out, out_size);
        return;
    }

    char* ws = (char*)d_ws;
    unsigned short* Wcomb = (unsigned short*)(ws + OFF_WCOMB);
    unsigned short* Wpin  = (unsigned short*)(ws + OFF_WPIN);
    unsigned short* Wpout = (unsigned short*)(ws + OFF_WPOUT);
    unsigned short* Wb    = (unsigned short*)(ws + OFF_WB);
    float* stats = (float*)(ws + OFF_STATS);
    float* G     = stats;
    float* nrm   = stats + 6144;
    float* attnW = stats + 6912;

    unsigned short* y1p      = (unsigned short*)(ws + OFF_A);     // padded [4][256][258][96]
    unsigned short* qkv      = (unsigned short*)(ws + OFF_B);
    unsigned short* xres     = (unsigned short*)(ws + OFF_C);
    unsigned short* y2       = (unsigned short*)(ws + OFF_C + SZ_XRES);
    float*          Gpart    = (float*)(ws + OFF_C + SZ_XRES);
    unsigned short* h1       = (unsigned short*)(ws + OFF_A);     // 192 MB, fits in [OFF_A, OFF_C)
    unsigned short* gated    = (unsigned short*)(ws + OFF_C);
    float* x2 = out;   // x2 lives in d_out as NCHW fp32; pout RMWs it into the final output

    // weight prep + pad fill
    k_combine_qkv<<<9 * 288, 96, 0, stream>>>(qkv2_w, qkv1_w, Wcomb);
    k_f32_to_bf16<<<(384 * 96 + 255) / 256, 256, 0, stream>>>(pin_w, Wpin, 384 * 96);
    k_f32_to_bf16<<<(96 * 192 + 255) / 256, 256, 0, stream>>>(pout_w, Wpout, 96 * 192);
    k_fillpad<<<384, 256, 0, stream>>>((unsigned*)y1p);

    // LN1 (+ NCHW->NHWC padded), residual snapshot
    k_ln1<<<NPOS / 64, 256, 0, stream>>>(x, ln1_w, ln1_b, xres, y1p);
    // combined qkv conv: 3x3, 96 -> 288 (counted-vmcnt pipeline)
    k_qkvconv<<<dim3(3, 2048), 256, 0, stream>>>(y1p, Wcomb, qkv);
    // attention stats + softmax
    k_attn_stats<<<NPOS / 256, 256, 0, stream>>>(qkv, Gpart);
    k_attn_reduce<<<27, 256, 0, stream>>>(Gpart, G, nrm);
    k_softmax<<<1, 384, 0, stream>>>(G, nrm, scale, attnW);
    // fold apply+proj: per-batch combined weight Wb = blockdiag(aw)^T * Wproj^T
    k_combine_wb<<<4 * 96, 96, 0, stream>>>(proj_w, attnW, Wb);
    // proj on V slice of qkv + residual(bf16) -> x2 (NCHW fp32 in d_out)
    k_gemm<96, 96, 2><<<dim3(2048, 1), 256, 0, stream>>>(qkv + 192, Wb, xres, x2, 288, 9216);
    // LN2 (reads NCHW)
    k_ln2n<<<NPOS / 64, 256, 0, stream>>>(x2, ln2_w, ln2_b, y2);
    // pin: 96 -> 384
    k_gemm<96, 384, 0><<<dim3(2048, 4), 256, 0, stream>>>(y2, Wpin, nullptr, h1, 96, 0);
    // grouped 3x3 + gelu gate
    k_dwgate<<<NPOS / 32, 192, 0, stream>>>(h1, dw_w, gated);
    // pout + residual(x2 NCHW, in-place) -> final NCHW in d_out
    k_gemm<192, 96, 1><<<dim3(2048, 1), 256, 0, stream>>>(gated, Wpout, x2, out, 192, 0);
}